// Round 7
// baseline (4905.468 us; speedup 1.0000x reference)
//
#include <hip/hip_runtime.h>

#define S 2048
#define DD 64
#define NH 32           // B*H
#define NW 8            // waves per block
#define KSLICE 256      // k columns per wave
#define NT 16           // 16-wide k tiles per wave

typedef float f32x4 __attribute__((ext_vector_type(4)));
typedef unsigned int u32x4 __attribute__((ext_vector_type(4)));
typedef short bf16x8 __attribute__((ext_vector_type(8)));

__device__ inline unsigned int packsplit(float x){
  unsigned int u = __float_as_uint(x);
  unsigned int h = u >> 16;
  float rem = x - __uint_as_float(h << 16);
  unsigned int l = __float_as_uint(rem) >> 16;
  return (h << 16) | l;
}
__device__ inline void split2(float x, short &hi, short &lo){
  unsigned int p = packsplit(x);
  hi = (short)(p >> 16); lo = (short)(p & 0xFFFFu);
}
__device__ inline f32x4 ntload4(const float* p){
  return __builtin_nontemporal_load(reinterpret_cast<const f32x4*>(p));
}
__device__ inline void ntstore4(float* p, f32x4 v){
  __builtin_nontemporal_store(v, reinterpret_cast<f32x4*>(p));
}

// ---- pre-pack kernels ----
__global__ void pack_k_kernel(const float* __restrict__ in, unsigned int* __restrict__ out, int n4){
  int i = blockIdx.x * 256 + threadIdx.x;
  if (i < n4){
    f32x4 x = ntload4(in + 4*(size_t)i);
    u32x4 p;
    p.x = packsplit(x.x); p.y = packsplit(x.y);
    p.z = packsplit(x.z); p.w = packsplit(x.w);
    reinterpret_cast<u32x4*>(out)[i] = p;
  }
}

__global__ void pack_vt_kernel(const float* __restrict__ v, unsigned int* __restrict__ vt){
  const int head = blockIdx.x >> 5;
  const int s0   = (blockIdx.x & 31) * 64;
  const float* vh = v + (size_t)head * S * DD;
  unsigned int* vth = vt + (size_t)head * DD * S;
  __shared__ unsigned int tile[64][65];
  const int tid = threadIdx.x;
  for (int i = tid; i < 64*64; i += 256){
    int s = i >> 6, d = i & 63;
    tile[d][s] = packsplit(__builtin_nontemporal_load(&vh[(size_t)(s0 + s) * DD + d]));
  }
  __syncthreads();
  for (int i = tid; i < 64*64; i += 256){
    int d = i >> 6, s = i & 63;
    vth[(size_t)d * S + s0 + s] = tile[d][s];
  }
}

// ---- fused attention, MODE-ablated ----
// MODE bits: 1=bias/gb stream read, 2=QK^T (K loads + MFMA), 4=weight store, 8=PV+out
template<bool PACKED, int MODE>
__global__ __launch_bounds__(512, 4)
void attn_fused_kernel(const float* __restrict__ q, const float* __restrict__ k,
                       const float* __restrict__ v, const float* __restrict__ bias,
                       const float* __restrict__ gb,
                       const unsigned int* __restrict__ kp,
                       const unsigned int* __restrict__ vtp,
                       float* __restrict__ out, float* __restrict__ wout)
{
  constexpr bool DO_BIAS = MODE & 1;
  constexpr bool DO_QK   = MODE & 2;
  constexpr bool DO_WST  = MODE & 4;
  constexpr bool DO_PV   = MODE & 8;

  const int head = blockIdx.y;
  const int q0   = blockIdx.x * 16;
  const int tid  = threadIdx.x;
  const int wid  = tid >> 6;
  const int lane = tid & 63;
  const int lr   = lane & 15;
  const int lg   = lane >> 4;

  const float* qh = q    + (size_t)head * S * DD;
  const float* kh = k    + (size_t)head * S * DD;
  const float* vh = v    + (size_t)head * S * DD;
  const float* bh = bias + (size_t)head * S * S;
  const float* gh = gb   + (size_t)head * S * S;
  const unsigned int* kph  = kp  + (size_t)head * S * DD;
  const unsigned int* vtph = vtp + (size_t)head * DD * S;
  float* oh = out  + (size_t)head * S * DD;
  float* wh = wout + (size_t)head * S * S;

  __shared__ unsigned int sW[NW][16][68];
  __shared__ float redm[NW][16];
  __shared__ float redl[NW][16];

  const int kw0 = wid * KSLICE;
  f32x4 acc[NT];

  // ---- Phase 0: acc init
  if constexpr (DO_BIAS){
    const float* brow = bh + (size_t)(q0 + lr) * S + kw0 + lg*4;
    const float* grow = gh + (size_t)(q0 + lr) * S + kw0 + lg*4;
#pragma unroll 4
    for (int t = 0; t < NT; ++t){
      f32x4 b4 = *reinterpret_cast<const f32x4*>(brow + 16*t);
      f32x4 g4 = *reinterpret_cast<const f32x4*>(grow + 16*t);
#pragma unroll
      for (int r = 0; r < 4; ++r)
        acc[t][r] = b4[r] - 0.5f * g4[r] * g4[r];
    }
  } else {
#pragma unroll
    for (int t = 0; t < NT; ++t)
#pragma unroll
      for (int r = 0; r < 4; ++r)
        acc[t][r] = 0.01f * (float)((lr*7 + r*3 + t) & 15);
  }

  // ---- Phase 1: QK^T
  if constexpr (DO_QK){
    bf16x8 qhi[2], qlo[2];
    {
      const float* qrow = qh + (size_t)(q0 + lr) * DD;
#pragma unroll
      for (int ks = 0; ks < 2; ++ks){
        float4 a = *reinterpret_cast<const float4*>(qrow + ks*32 + lg*8);
        float4 b = *reinterpret_cast<const float4*>(qrow + ks*32 + lg*8 + 4);
        float f[8] = {a.x,a.y,a.z,a.w,b.x,b.y,b.z,b.w};
#pragma unroll
        for (int j = 0; j < 8; ++j){
          short h, l2; split2(f[j] * 0.125f, h, l2);
          qhi[ks][j] = h; qlo[ks][j] = l2;
        }
      }
    }
#pragma unroll 2
    for (int t = 0; t < NT; ++t){
      const int kbase = kw0 + 16*t;
      bf16x8 khi[2], klo[2];
      if constexpr (PACKED){
        const unsigned int* kr = kph + (size_t)(kbase + lr) * DD;
#pragma unroll
        for (int ks = 0; ks < 2; ++ks){
          uint4 p0 = *reinterpret_cast<const uint4*>(kr + ks*32 + lg*8);
          uint4 p1 = *reinterpret_cast<const uint4*>(kr + ks*32 + lg*8 + 4);
          unsigned int pw[8] = {p0.x,p0.y,p0.z,p0.w,p1.x,p1.y,p1.z,p1.w};
#pragma unroll
          for (int j = 0; j < 8; ++j){
            khi[ks][j] = (short)(pw[j] >> 16);
            klo[ks][j] = (short)(pw[j] & 0xFFFFu);
          }
        }
      } else {
        const float* krow = kh + (size_t)(kbase + lr) * DD;
#pragma unroll
        for (int ks = 0; ks < 2; ++ks){
          float4 a = *reinterpret_cast<const float4*>(krow + ks*32 + lg*8);
          float4 b = *reinterpret_cast<const float4*>(krow + ks*32 + lg*8 + 4);
          float f[8] = {a.x,a.y,a.z,a.w,b.x,b.y,b.z,b.w};
#pragma unroll
          for (int j = 0; j < 8; ++j){
            short h, l2; split2(f[j], h, l2);
            khi[ks][j] = h; klo[ks][j] = l2;
          }
        }
      }
#pragma unroll
      for (int ks = 0; ks < 2; ++ks){
        acc[t] = __builtin_amdgcn_mfma_f32_16x16x32_bf16(klo[ks], qhi[ks], acc[t], 0,0,0);
        acc[t] = __builtin_amdgcn_mfma_f32_16x16x32_bf16(khi[ks], qlo[ks], acc[t], 0,0,0);
        acc[t] = __builtin_amdgcn_mfma_f32_16x16x32_bf16(khi[ks], qhi[ks], acc[t], 0,0,0);
      }
    }
  }

  // ---- Phase 2: softmax (always)
  float mrow;
  {
    float mm = -3.4e38f;
#pragma unroll
    for (int t = 0; t < NT; ++t)
#pragma unroll
      for (int r = 0; r < 4; ++r) mm = fmaxf(mm, acc[t][r]);
    mm = fmaxf(mm, __shfl_xor(mm, 16, 64));
    mm = fmaxf(mm, __shfl_xor(mm, 32, 64));
    if (lane < 16) redm[wid][lane] = mm;
  }
  __syncthreads();
  {
    float mm = redm[0][lr];
#pragma unroll
    for (int w = 1; w < NW; ++w) mm = fmaxf(mm, redm[w][lr]);
    mrow = mm;
  }

  float inv;
  {
    float s = 0.f;
#pragma unroll
    for (int t = 0; t < NT; ++t)
#pragma unroll
      for (int r = 0; r < 4; ++r){
        float e = __expf(acc[t][r] - mrow);
        acc[t][r] = e;
        s += e;
      }
    s += __shfl_xor(s, 16, 64);
    s += __shfl_xor(s, 32, 64);
    if (lane < 16) redl[wid][lane] = s;
    __syncthreads();
    float tot = 0.f;
#pragma unroll
    for (int w = 0; w < NW; ++w) tot += redl[w][lr];
    inv = 1.0f / tot;
  }

  // ---- Phase 3+4
  f32x4 oacc[4];
#pragma unroll
  for (int n = 0; n < 4; ++n) oacc[n] = (f32x4){0.f,0.f,0.f,0.f};

  float* wrow = wh + (size_t)(q0 + lr) * S + kw0 + lg*4;

#pragma unroll 1
  for (int c = 0; c < 4; ++c){
#pragma unroll
    for (int tt = 0; tt < 4; ++tt){
      const int t = 4*c + tt;
      if constexpr (DO_PV){
        u32x4 pw;
#pragma unroll
        for (int r = 0; r < 4; ++r)
          pw[r] = packsplit(acc[t][r] * inv);
        *reinterpret_cast<u32x4*>(&sW[wid][lr][16*tt + lg*4]) = pw;
      }
      if constexpr (DO_WST){
        f32x4 w4;
#pragma unroll
        for (int r = 0; r < 4; ++r)
          w4[r] = acc[t][r] * inv;
        ntstore4(wrow + 16*t, w4);
      }
    }
    if constexpr (DO_PV){
      const int kc = kw0 + 64*c;
#pragma unroll
      for (int ks = 0; ks < 2; ++ks){
        uint4 pa0 = *reinterpret_cast<const uint4*>(&sW[wid][lr][32*ks + lg*8]);
        uint4 pa1 = *reinterpret_cast<const uint4*>(&sW[wid][lr][32*ks + lg*8 + 4]);
        unsigned int pa[8] = {pa0.x,pa0.y,pa0.z,pa0.w,pa1.x,pa1.y,pa1.z,pa1.w};
        bf16x8 ahi, alo;
#pragma unroll
        for (int j = 0; j < 8; ++j){
          ahi[j] = (short)(pa[j] >> 16);
          alo[j] = (short)(pa[j] & 0xFFFFu);
        }
#pragma unroll
        for (int n = 0; n < 4; ++n){
          bf16x8 bhi, blo;
          if constexpr (PACKED){
            const unsigned int* vrow = vtph + (size_t)(16*n + lr) * S + kc + 32*ks + lg*8;
            uint4 p0 = *reinterpret_cast<const uint4*>(vrow);
            uint4 p1 = *reinterpret_cast<const uint4*>(vrow + 4);
            unsigned int pw[8] = {p0.x,p0.y,p0.z,p0.w,p1.x,p1.y,p1.z,p1.w};
#pragma unroll
            for (int j = 0; j < 8; ++j){
              bhi[j] = (short)(pw[j] >> 16);
              blo[j] = (short)(pw[j] & 0xFFFFu);
            }
          } else {
#pragma unroll
            for (int j = 0; j < 8; ++j){
              float x = vh[(size_t)(kc + 32*ks + lg*8 + j) * DD + 16*n + lr];
              short h, l2; split2(x, h, l2);
              bhi[j] = h; blo[j] = l2;
            }
          }
          oacc[n] = __builtin_amdgcn_mfma_f32_16x16x32_bf16(alo, bhi, oacc[n], 0,0,0);
          oacc[n] = __builtin_amdgcn_mfma_f32_16x16x32_bf16(ahi, blo, oacc[n], 0,0,0);
          oacc[n] = __builtin_amdgcn_mfma_f32_16x16x32_bf16(ahi, bhi, oacc[n], 0,0,0);
        }
      }
    }
  }

  // ---- Phase 5
  if constexpr (DO_PV){
    float (*sO)[16][68] = reinterpret_cast<float(*)[16][68]>(sW);
    __syncthreads();
#pragma unroll
    for (int n = 0; n < 4; ++n)
#pragma unroll
      for (int r = 0; r < 4; ++r)
        sO[wid][lg*4 + r][16*n + lr] = oacc[n][r];
    __syncthreads();
#pragma unroll
    for (int i = tid; i < 16*64; i += 512){
      int row = i >> 6, d = i & 63;
      float s = 0.f;
#pragma unroll
      for (int w = 0; w < NW; ++w) s += sO[w][row][d];
      __builtin_nontemporal_store(s, &oh[(size_t)(q0 + row) * DD + d]);
    }
  }
}

extern "C" void kernel_launch(void* const* d_in, const int* in_sizes, int n_in,
                              void* d_out, int out_size, void* d_ws, size_t ws_size,
                              hipStream_t stream) {
  const float* q    = (const float*)d_in[0];
  const float* k    = (const float*)d_in[1];
  const float* v    = (const float*)d_in[2];
  const float* bias = (const float*)d_in[3];
  const float* gb   = (const float*)d_in[4];
  float* out  = (float*)d_out;
  float* wout = (float*)d_out + (size_t)NH * S * DD;

  const size_t nelem = (size_t)NH * S * DD;       // 4.19M
  const size_t need  = 2 * nelem * sizeof(unsigned int);

  dim3 grid(S / 16, NH);
  dim3 block(512);

  if (ws_size >= need){
    unsigned int* kp  = (unsigned int*)d_ws;
    unsigned int* vtp = kp + nelem;
    int n4 = (int)(nelem / 4);
    pack_k_kernel<<<(n4 + 255) / 256, 256, 0, stream>>>(k, kp, n4);
    pack_vt_kernel<<<NH * 32, 256, 0, stream>>>(v, vtp);
    // ---- ablation probes (outputs overwritten by the final full dispatch) ----
    // V4: pure memory floor — bias/gb stream in + weight stream out, no MFMA
    attn_fused_kernel<true, 1|4    ><<<grid, block, 0, stream>>>(q, k, v, bias, gb, kp, vtp, out, wout);
    // V3: no PV (QK + bias + wstore)
    attn_fused_kernel<true, 1|2|4  ><<<grid, block, 0, stream>>>(q, k, v, bias, gb, kp, vtp, out, wout);
    // V2: no bias-read (QK + wstore + PV)
    attn_fused_kernel<true, 2|4|8  ><<<grid, block, 0, stream>>>(q, k, v, bias, gb, kp, vtp, out, wout);
    // V1: no weight-store (bias + QK + PV)
    attn_fused_kernel<true, 1|2|8  ><<<grid, block, 0, stream>>>(q, k, v, bias, gb, kp, vtp, out, wout);
    // V0: FULL — must be LAST so d_out is correct
    attn_fused_kernel<true, 15     ><<<grid, block, 0, stream>>>(q, k, v, bias, gb, kp, vtp, out, wout);
  } else {
    attn_fused_kernel<false, 15><<<grid, block, 0, stream>>>(q, k, v, bias, gb, nullptr, nullptr, out, wout);
  }
}

// Round 9
// 1394.516 us; speedup vs baseline: 3.5177x; 3.5177x over previous
//
#include <hip/hip_runtime.h>

#define S 2048
#define DD 64
#define NH 32           // B*H
#define NW 8            // waves per block
#define KSLICE 256      // k columns per wave
#define NT 16           // 16-wide k tiles per wave
#define CH 256          // staging chunk columns

typedef float f32x4 __attribute__((ext_vector_type(4)));
typedef unsigned int u32x4 __attribute__((ext_vector_type(4)));
typedef short bf16x8 __attribute__((ext_vector_type(8)));

__device__ inline unsigned int packsplit(float x){
  unsigned int u = __float_as_uint(x);
  unsigned int h = u >> 16;
  float rem = x - __uint_as_float(h << 16);
  unsigned int l = __float_as_uint(rem) >> 16;
  return (h << 16) | l;
}
__device__ inline void split2(float x, short &hi, short &lo){
  unsigned int p = packsplit(x);
  hi = (short)(p >> 16); lo = (short)(p & 0xFFFFu);
}
__device__ inline f32x4 ntload4(const float* p){
  return __builtin_nontemporal_load(reinterpret_cast<const f32x4*>(p));
}
__device__ inline void ntstore4(float* p, f32x4 v){
  __builtin_nontemporal_store(v, reinterpret_cast<f32x4*>(p));
}

// ---- pre-pack kernels ----
__global__ void pack_k_kernel(const float* __restrict__ in, unsigned int* __restrict__ out, int n4){
  int i = blockIdx.x * 256 + threadIdx.x;
  if (i < n4){
    f32x4 x = ntload4(in + 4*(size_t)i);
    u32x4 p;
    p.x = packsplit(x.x); p.y = packsplit(x.y);
    p.z = packsplit(x.z); p.w = packsplit(x.w);
    reinterpret_cast<u32x4*>(out)[i] = p;
  }
}

__global__ void pack_vt_kernel(const float* __restrict__ v, unsigned int* __restrict__ vt){
  const int head = blockIdx.x >> 5;
  const int s0   = (blockIdx.x & 31) * 64;
  const float* vh = v + (size_t)head * S * DD;
  unsigned int* vth = vt + (size_t)head * DD * S;
  __shared__ unsigned int tile[64][65];
  const int tid = threadIdx.x;
  for (int i = tid; i < 64*64; i += 256){
    int s = i >> 6, d = i & 63;
    tile[d][s] = packsplit(__builtin_nontemporal_load(&vh[(size_t)(s0 + s) * DD + d]));
  }
  __syncthreads();
  for (int i = tid; i < 64*64; i += 256){
    int d = i >> 6, s = i & 63;
    vth[(size_t)d * S + s0 + s] = tile[d][s];
  }
}

// ---- fused attention ----
template<bool PACKED>
__global__ __launch_bounds__(512, 4)   // pin regs <=128/wave: 2 blocks/CU
void attn_fused_kernel(const float* __restrict__ q, const float* __restrict__ k,
                       const float* __restrict__ v, const float* __restrict__ bias,
                       const float* __restrict__ gb,
                       const unsigned int* __restrict__ kp,
                       const unsigned int* __restrict__ vtp,
                       float* __restrict__ out, float* __restrict__ wout)
{
  const int head = blockIdx.y;
  const int q0   = blockIdx.x * 16;
  const int tid  = threadIdx.x;
  const int wid  = tid >> 6;
  const int lane = tid & 63;
  const int lr   = lane & 15;
  const int lg   = lane >> 4;

  const float* qh = q    + (size_t)head * S * DD;
  const float* kh = k    + (size_t)head * S * DD;
  const float* vh = v    + (size_t)head * S * DD;
  const float* bh = bias + (size_t)head * S * S;
  const float* gh = gb   + (size_t)head * S * S;
  const unsigned int* kph  = kp  + (size_t)head * S * DD;
  const unsigned int* vtph = vtp + (size_t)head * DD * S;
  float* oh = out  + (size_t)head * S * DD;
  float* wh = wout + (size_t)head * S * S;

  __shared__ unsigned int sW[NW][16][68];   // 34.8 KB: PV packed weights (per-wave)
  __shared__ float stg[2][16][CH];          // 32 KB: double-buffered stream tile
  __shared__ float redm[NW][16];
  __shared__ float redl[NW][16];

  const int kw0 = wid * KSLICE;
  f32x4 acc[NT];

  const int r0 = 2*wid;        // this wave's cooperative stream rows
  const int r1 = 2*wid + 1;
  const int p0 = 4 * (lane ^ (r0 & 7));   // swizzled LDS dword for fill, row r0
  const int p1 = 4 * (lane ^ (r1 & 7));

  // ---- Phase 0: bias - 0.5*g^2 via coalesced staged pipeline.
  // chunk i: tensor = i&1 (0=bias,1=gb), cols [(i>>1)*CH, +CH). Fill: 1KB
  // contiguous per instr per row. Consume: owner wave (i>>1) -> its acc frags.
  {
    f32x4 pre_a = ntload4(bh + (size_t)(q0 + r0) * S + 4*lane);
    f32x4 pre_b = ntload4(bh + (size_t)(q0 + r1) * S + 4*lane);
#pragma unroll 1
    for (int i = 0; i < 16; ++i){
      const int b = i & 1;
      *reinterpret_cast<f32x4*>(&stg[b][r0][p0]) = pre_a;
      *reinterpret_cast<f32x4*>(&stg[b][r1][p1]) = pre_b;
      if (i < 15){
        const int ni = i + 1;
        const float* base = (ni & 1) ? gh : bh;
        const size_t off = (size_t)(ni >> 1) * CH + 4*lane;
        pre_a = ntload4(base + (size_t)(q0 + r0) * S + off);
        pre_b = ntload4(base + (size_t)(q0 + r1) * S + off);
      }
      __syncthreads();
      if (wid == (i >> 1)){
        if ((i & 1) == 0){
#pragma unroll
          for (int t = 0; t < NT; ++t){
            const int dw = (16*t + 4*lg) ^ ((lr & 7) << 2);
            acc[t] = *reinterpret_cast<const f32x4*>(&stg[b][lr][dw]);
          }
        } else {
#pragma unroll
          for (int t = 0; t < NT; ++t){
            const int dw = (16*t + 4*lg) ^ ((lr & 7) << 2);
            f32x4 g4 = *reinterpret_cast<const f32x4*>(&stg[b][lr][dw]);
#pragma unroll
            for (int r = 0; r < 4; ++r)
              acc[t][r] -= 0.5f * g4[r] * g4[r];
          }
        }
      }
    }
  }

  // ---- Q fragments (B operand: lane holds Q[q0+lr][32ks + lg*8+j]), pre-scaled
  bf16x8 qhi[2], qlo[2];
  {
    const float* qrow = qh + (size_t)(q0 + lr) * DD;
#pragma unroll
    for (int ks = 0; ks < 2; ++ks){
      float4 a = *reinterpret_cast<const float4*>(qrow + ks*32 + lg*8);
      float4 b = *reinterpret_cast<const float4*>(qrow + ks*32 + lg*8 + 4);
      float f[8] = {a.x,a.y,a.z,a.w,b.x,b.y,b.z,b.w};
#pragma unroll
      for (int j = 0; j < 8; ++j){
        short h, l2; split2(f[j] * 0.125f, h, l2);
        qhi[ks][j] = h; qlo[ks][j] = l2;
      }
    }
  }

  // ---- Phase 1: QK^T on top of bias-initialized acc (K is L2-resident)
#pragma unroll 2
  for (int t = 0; t < NT; ++t){
    const int kbase = kw0 + 16*t;
    bf16x8 khi[2], klo[2];
    if constexpr (PACKED){
      const unsigned int* kr = kph + (size_t)(kbase + lr) * DD;
#pragma unroll
      for (int ks = 0; ks < 2; ++ks){
        uint4 pa = *reinterpret_cast<const uint4*>(kr + ks*32 + lg*8);
        uint4 pb = *reinterpret_cast<const uint4*>(kr + ks*32 + lg*8 + 4);
        unsigned int pw[8] = {pa.x,pa.y,pa.z,pa.w,pb.x,pb.y,pb.z,pb.w};
#pragma unroll
        for (int j = 0; j < 8; ++j){
          khi[ks][j] = (short)(pw[j] >> 16);
          klo[ks][j] = (short)(pw[j] & 0xFFFFu);
        }
      }
    } else {
      const float* krow = kh + (size_t)(kbase + lr) * DD;
#pragma unroll
      for (int ks = 0; ks < 2; ++ks){
        float4 a = *reinterpret_cast<const float4*>(krow + ks*32 + lg*8);
        float4 b = *reinterpret_cast<const float4*>(krow + ks*32 + lg*8 + 4);
        float f[8] = {a.x,a.y,a.z,a.w,b.x,b.y,b.z,b.w};
#pragma unroll
        for (int j = 0; j < 8; ++j){
          short h, l2; split2(f[j], h, l2);
          khi[ks][j] = h; klo[ks][j] = l2;
        }
      }
    }
#pragma unroll
    for (int ks = 0; ks < 2; ++ks){
      acc[t] = __builtin_amdgcn_mfma_f32_16x16x32_bf16(klo[ks], qhi[ks], acc[t], 0,0,0);
      acc[t] = __builtin_amdgcn_mfma_f32_16x16x32_bf16(khi[ks], qlo[ks], acc[t], 0,0,0);
      acc[t] = __builtin_amdgcn_mfma_f32_16x16x32_bf16(khi[ks], qhi[ks], acc[t], 0,0,0);
    }
  }

  // ---- Phase 2: softmax. Row q0+lr fully owned along (lg, r, t, wave).
  float mrow;
  {
    float mm = -3.4e38f;
#pragma unroll
    for (int t = 0; t < NT; ++t)
#pragma unroll
      for (int r = 0; r < 4; ++r) mm = fmaxf(mm, acc[t][r]);
    mm = fmaxf(mm, __shfl_xor(mm, 16, 64));
    mm = fmaxf(mm, __shfl_xor(mm, 32, 64));
    if (lane < 16) redm[wid][lane] = mm;
  }
  __syncthreads();
  {
    float mm = redm[0][lr];
#pragma unroll
    for (int w = 1; w < NW; ++w) mm = fmaxf(mm, redm[w][lr]);
    mrow = mm;
  }

  float inv;
  {
    float s = 0.f;
#pragma unroll
    for (int t = 0; t < NT; ++t)
#pragma unroll
      for (int r = 0; r < 4; ++r){
        float e = __expf(acc[t][r] - mrow);
        acc[t][r] = e;
        s += e;
      }
    s += __shfl_xor(s, 16, 64);
    s += __shfl_xor(s, 32, 64);
    if (lane < 16) redl[wid][lane] = s;
    __syncthreads();
    float tot = 0.f;
#pragma unroll
    for (int w = 0; w < NW; ++w) tot += redl[w][lr];
    inv = 1.0f / tot;
  }

  // ---- Phase 3: PV (sW pack + MFMA), per-wave, no barriers
  f32x4 oacc[4];
#pragma unroll
  for (int n = 0; n < 4; ++n) oacc[n] = (f32x4){0.f,0.f,0.f,0.f};

#pragma unroll 1
  for (int c = 0; c < 4; ++c){
#pragma unroll
    for (int tt = 0; tt < 4; ++tt){
      const int t = 4*c + tt;
      u32x4 pw;
#pragma unroll
      for (int r = 0; r < 4; ++r)
        pw[r] = packsplit(acc[t][r] * inv);
      *reinterpret_cast<u32x4*>(&sW[wid][lr][16*tt + lg*4]) = pw;
    }
    const int kc = kw0 + 64*c;
#pragma unroll
    for (int ks = 0; ks < 2; ++ks){
      uint4 pa0 = *reinterpret_cast<const uint4*>(&sW[wid][lr][32*ks + lg*8]);
      uint4 pa1 = *reinterpret_cast<const uint4*>(&sW[wid][lr][32*ks + lg*8 + 4]);
      unsigned int pa[8] = {pa0.x,pa0.y,pa0.z,pa0.w,pa1.x,pa1.y,pa1.z,pa1.w};
      bf16x8 ahi, alo;
#pragma unroll
      for (int j = 0; j < 8; ++j){
        ahi[j] = (short)(pa[j] >> 16);
        alo[j] = (short)(pa[j] & 0xFFFFu);
      }
#pragma unroll
      for (int n = 0; n < 4; ++n){
        bf16x8 bhi, blo;
        if constexpr (PACKED){
          const unsigned int* vrow = vtph + (size_t)(16*n + lr) * S + kc + 32*ks + lg*8;
          uint4 pv0 = *reinterpret_cast<const uint4*>(vrow);
          uint4 pv1 = *reinterpret_cast<const uint4*>(vrow + 4);
          unsigned int pw[8] = {pv0.x,pv0.y,pv0.z,pv0.w,pv1.x,pv1.y,pv1.z,pv1.w};
#pragma unroll
          for (int j = 0; j < 8; ++j){
            bhi[j] = (short)(pw[j] >> 16);
            blo[j] = (short)(pw[j] & 0xFFFFu);
          }
        } else {
#pragma unroll
          for (int j = 0; j < 8; ++j){
            float x = vh[(size_t)(kc + 32*ks + lg*8 + j) * DD + 16*n + lr];
            short h, l2; split2(x, h, l2);
            bhi[j] = h; blo[j] = l2;
          }
        }
        oacc[n] = __builtin_amdgcn_mfma_f32_16x16x32_bf16(alo, bhi, oacc[n], 0,0,0);
        oacc[n] = __builtin_amdgcn_mfma_f32_16x16x32_bf16(ahi, blo, oacc[n], 0,0,0);
        oacc[n] = __builtin_amdgcn_mfma_f32_16x16x32_bf16(ahi, bhi, oacc[n], 0,0,0);
      }
    }
  }

  // ---- Phase 3b: coalesced weight write-out pipeline (reuses stg).
  // deposit(h): owner wave h writes its 16x256 fp32 tile into stg[h&1]
  // writeout(h): all waves store rows 2w,2w+1 as 1KB contiguous nt stores.
  {
    __syncthreads();   // PV reads of sW done block-wide before stg reuse timing
    if (wid == 0){
#pragma unroll
      for (int t = 0; t < NT; ++t){
        const int dw = (16*t + 4*lg) ^ ((lr & 7) << 2);
        f32x4 w4;
#pragma unroll
        for (int r = 0; r < 4; ++r) w4[r] = acc[t][r] * inv;
        *reinterpret_cast<f32x4*>(&stg[0][lr][dw]) = w4;
      }
    }
    __syncthreads();
#pragma unroll 1
    for (int h = 0; h < 8; ++h){
      if (h < 7 && wid == h + 1){
        const int nb = (h + 1) & 1;
#pragma unroll
        for (int t = 0; t < NT; ++t){
          const int dw = (16*t + 4*lg) ^ ((lr & 7) << 2);
          f32x4 w4;
#pragma unroll
          for (int r = 0; r < 4; ++r) w4[r] = acc[t][r] * inv;
          *reinterpret_cast<f32x4*>(&stg[nb][lr][dw]) = w4;
        }
      }
      {
        const int b = h & 1;
        f32x4 w0 = *reinterpret_cast<const f32x4*>(&stg[b][r0][p0]);
        f32x4 w1 = *reinterpret_cast<const f32x4*>(&stg[b][r1][p1]);
        ntstore4(wh + (size_t)(q0 + r0) * S + (size_t)h * CH + 4*lane, w0);
        ntstore4(wh + (size_t)(q0 + r1) * S + (size_t)h * CH + 4*lane, w1);
      }
      __syncthreads();
    }
  }

  // ---- Phase 5: cross-wave reduction of out partials (alias sW)
  float (*sO)[16][68] = reinterpret_cast<float(*)[16][68]>(sW);
#pragma unroll
  for (int n = 0; n < 4; ++n)
#pragma unroll
    for (int r = 0; r < 4; ++r)
      sO[wid][lg*4 + r][16*n + lr] = oacc[n][r];
  __syncthreads();
#pragma unroll
  for (int i = tid; i < 16*64; i += 512){
    int row = i >> 6, d = i & 63;
    float s = 0.f;
#pragma unroll
    for (int w = 0; w < NW; ++w) s += sO[w][row][d];
    __builtin_nontemporal_store(s, &oh[(size_t)(q0 + row) * DD + d]);
  }
}

extern "C" void kernel_launch(void* const* d_in, const int* in_sizes, int n_in,
                              void* d_out, int out_size, void* d_ws, size_t ws_size,
                              hipStream_t stream) {
  const float* q    = (const float*)d_in[0];
  const float* k    = (const float*)d_in[1];
  const float* v    = (const float*)d_in[2];
  const float* bias = (const float*)d_in[3];
  const float* gb   = (const float*)d_in[4];
  float* out  = (float*)d_out;
  float* wout = (float*)d_out + (size_t)NH * S * DD;

  const size_t nelem = (size_t)NH * S * DD;       // 4.19M
  const size_t need  = 2 * nelem * sizeof(unsigned int);

  dim3 grid(S / 16, NH);
  dim3 block(512);

  if (ws_size >= need){
    unsigned int* kp  = (unsigned int*)d_ws;
    unsigned int* vtp = kp + nelem;
    int n4 = (int)(nelem / 4);
    pack_k_kernel<<<(n4 + 255) / 256, 256, 0, stream>>>(k, kp, n4);
    pack_vt_kernel<<<NH * 32, 256, 0, stream>>>(v, vtp);
    attn_fused_kernel<true ><<<grid, block, 0, stream>>>(q, k, v, bias, gb, kp, vtp, out, wout);
  } else {
    attn_fused_kernel<false><<<grid, block, 0, stream>>>(q, k, v, bias, gb, nullptr, nullptr, out, wout);
  }
}

// Round 10
// 1197.814 us; speedup vs baseline: 4.0953x; 1.1642x over previous
//
#include <hip/hip_runtime.h>

#define S 2048
#define DD 64
#define NH 32           // B*H
#define NW 8            // waves per block
#define KSLICE 256      // k columns per wave
#define NT 16           // 16-wide k tiles per wave

typedef float f32x4 __attribute__((ext_vector_type(4)));
typedef unsigned int u32x4 __attribute__((ext_vector_type(4)));
typedef short bf16x8 __attribute__((ext_vector_type(8)));

__device__ inline unsigned int packsplit(float x){
  unsigned int u = __float_as_uint(x);
  unsigned int h = u >> 16;
  float rem = x - __uint_as_float(h << 16);
  unsigned int l = __float_as_uint(rem) >> 16;
  return (h << 16) | l;
}
__device__ inline void split2(float x, short &hi, short &lo){
  unsigned int p = packsplit(x);
  hi = (short)(p >> 16); lo = (short)(p & 0xFFFFu);
}
__device__ inline f32x4 ntload4(const float* p){
  return __builtin_nontemporal_load(reinterpret_cast<const f32x4*>(p));
}
__device__ inline void ntstore4(float* p, f32x4 v){
  __builtin_nontemporal_store(v, reinterpret_cast<f32x4*>(p));
}
// async global->LDS DMA: 16B per lane, LDS dest = wave-uniform base + lane*16
__device__ inline void gload_lds16(const float* g, float* l){
  __builtin_amdgcn_global_load_lds(
      (const __attribute__((address_space(1))) void*)g,
      (__attribute__((address_space(3))) void*)l, 16, 0, 0);
}

// ---- pre-pack kernels ----
__global__ void pack_k_kernel(const float* __restrict__ in, unsigned int* __restrict__ out, int n4){
  int i = blockIdx.x * 256 + threadIdx.x;
  if (i < n4){
    f32x4 x = ntload4(in + 4*(size_t)i);
    u32x4 p;
    p.x = packsplit(x.x); p.y = packsplit(x.y);
    p.z = packsplit(x.z); p.w = packsplit(x.w);
    reinterpret_cast<u32x4*>(out)[i] = p;
  }
}

__global__ void pack_vt_kernel(const float* __restrict__ v, unsigned int* __restrict__ vt){
  const int head = blockIdx.x >> 5;
  const int s0   = (blockIdx.x & 31) * 64;
  const float* vh = v + (size_t)head * S * DD;
  unsigned int* vth = vt + (size_t)head * DD * S;
  __shared__ unsigned int tile[64][65];
  const int tid = threadIdx.x;
  for (int i = tid; i < 64*64; i += 256){
    int s = i >> 6, d = i & 63;
    tile[d][s] = packsplit(__builtin_nontemporal_load(&vh[(size_t)(s0 + s) * DD + d]));
  }
  __syncthreads();
  for (int i = tid; i < 64*64; i += 256){
    int d = i >> 6, s = i & 63;
    vth[(size_t)d * S + s0 + s] = tile[d][s];
  }
}

// ---- fused attention ----
template<bool PACKED>
__global__ __launch_bounds__(512, 4)   // pin regs <=128/wave: 2 blocks/CU
void attn_fused_kernel(const float* __restrict__ q, const float* __restrict__ k,
                       const float* __restrict__ v, const float* __restrict__ bias,
                       const float* __restrict__ gb,
                       const unsigned int* __restrict__ kp,
                       const unsigned int* __restrict__ vtp,
                       float* __restrict__ out, float* __restrict__ wout)
{
  const int head = blockIdx.y;
  const int q0   = blockIdx.x * 16;
  const int tid  = threadIdx.x;
  const int wid  = tid >> 6;
  const int lane = tid & 63;
  const int lr   = lane & 15;
  const int lg   = lane >> 4;

  const float* qh = q    + (size_t)head * S * DD;
  const float* kh = k    + (size_t)head * S * DD;
  const float* vh = v    + (size_t)head * S * DD;
  const float* bh = bias + (size_t)head * S * S;
  const float* gh = gb   + (size_t)head * S * S;
  const unsigned int* kph  = kp  + (size_t)head * S * DD;
  const unsigned int* vtph = vtp + (size_t)head * DD * S;
  float* oh = out  + (size_t)head * S * DD;
  float* wh = wout + (size_t)head * S * S;

  __shared__ unsigned int sW[NW][16][68];     // 34.8 KB
  __shared__ float stg[4][NW][2][2][64];      // 32 KB: 4-buffer DMA ring
  __shared__ float redm[NW][16];
  __shared__ float redl[NW][16];

  const int kw0 = wid * KSLICE;
  f32x4 acc[NT];

  // ---- Phase 0: acc[t] = bias - 0.5*g^2 via global_load_lds + counted vmcnt.
  // Chunk c (c=0..31) = cols [64c, 64c+64). One DMA per wave per chunk:
  // lane = T*32 + rr*16 + g16 -> tensor T (0=bias,1=gb), row 2*wid+rr, 16B grp g16.
  {
    const int T   = lane >> 5;
    const int rr  = (lane >> 4) & 1;
    const int g16 = lane & 15;
    const float* srow = (T ? gh : bh) + (size_t)(q0 + 2*wid + rr) * S + 4*g16;

    // prologue: issue chunks 0..3 (buffers 0..3), 4 DMAs in flight
#pragma unroll
    for (int cc = 0; cc < 4; ++cc)
      gload_lds16(srow + 64*cc, &stg[cc][wid][0][0][0]);

#pragma unroll
    for (int c = 0; c < 32; ++c){
      // wait for own chunk-c DMA (up to 3 newer stay in flight)
      if      (c < 29) __builtin_amdgcn_s_waitcnt(0x0F73);   // vmcnt(3)
      else if (c == 29) __builtin_amdgcn_s_waitcnt(0x0F72);  // vmcnt(2)
      else if (c == 30) __builtin_amdgcn_s_waitcnt(0x0F71);  // vmcnt(1)
      else              __builtin_amdgcn_s_waitcnt(0x0F70);  // vmcnt(0)
      __builtin_amdgcn_sched_barrier(0);
      __builtin_amdgcn_s_barrier();            // chunk c visible block-wide
      __builtin_amdgcn_sched_barrier(0);
      if (wid == (c >> 2)){                    // owner folds into its acc
#pragma unroll
        for (int tt = 0; tt < 4; ++tt){
          f32x4 b4 = *reinterpret_cast<const f32x4*>(&stg[c & 3][lr >> 1][0][lr & 1][16*tt + 4*lg]);
          f32x4 g4 = *reinterpret_cast<const f32x4*>(&stg[c & 3][lr >> 1][1][lr & 1][16*tt + 4*lg]);
#pragma unroll
          for (int r = 0; r < 4; ++r)
            acc[(c & 3)*4 + tt][r] = b4[r] - 0.5f * g4[r] * g4[r];
        }
      }
      asm volatile("s_waitcnt lgkmcnt(0)" ::: "memory");
      __builtin_amdgcn_sched_barrier(0);
      __builtin_amdgcn_s_barrier();            // consume done; buffer reusable
      __builtin_amdgcn_sched_barrier(0);
      if (c + 4 < 32)
        gload_lds16(srow + 64*(c + 4), &stg[c & 3][wid][0][0][0]);
    }
  }

  // ---- Q fragments (B operand: lane holds Q[q0+lr][32ks + lg*8+j]), pre-scaled
  bf16x8 qhi[2], qlo[2];
  {
    const float* qrow = qh + (size_t)(q0 + lr) * DD;
#pragma unroll
    for (int ks = 0; ks < 2; ++ks){
      float4 a = *reinterpret_cast<const float4*>(qrow + ks*32 + lg*8);
      float4 b = *reinterpret_cast<const float4*>(qrow + ks*32 + lg*8 + 4);
      float f[8] = {a.x,a.y,a.z,a.w,b.x,b.y,b.z,b.w};
#pragma unroll
      for (int j = 0; j < 8; ++j){
        short h, l2; split2(f[j] * 0.125f, h, l2);
        qhi[ks][j] = h; qlo[ks][j] = l2;
      }
    }
  }

  // ---- Phase 1: QK^T on top of bias-initialized acc (K is L2-resident)
#pragma unroll 2
  for (int t = 0; t < NT; ++t){
    const int kbase = kw0 + 16*t;
    bf16x8 khi[2], klo[2];
    if constexpr (PACKED){
      const unsigned int* kr = kph + (size_t)(kbase + lr) * DD;
#pragma unroll
      for (int ks = 0; ks < 2; ++ks){
        uint4 pa = *reinterpret_cast<const uint4*>(kr + ks*32 + lg*8);
        uint4 pb = *reinterpret_cast<const uint4*>(kr + ks*32 + lg*8 + 4);
        unsigned int pw[8] = {pa.x,pa.y,pa.z,pa.w,pb.x,pb.y,pb.z,pb.w};
#pragma unroll
        for (int j = 0; j < 8; ++j){
          khi[ks][j] = (short)(pw[j] >> 16);
          klo[ks][j] = (short)(pw[j] & 0xFFFFu);
        }
      }
    } else {
      const float* krow = kh + (size_t)(kbase + lr) * DD;
#pragma unroll
      for (int ks = 0; ks < 2; ++ks){
        float4 a = *reinterpret_cast<const float4*>(krow + ks*32 + lg*8);
        float4 b = *reinterpret_cast<const float4*>(krow + ks*32 + lg*8 + 4);
        float f[8] = {a.x,a.y,a.z,a.w,b.x,b.y,b.z,b.w};
#pragma unroll
        for (int j = 0; j < 8; ++j){
          short h, l2; split2(f[j], h, l2);
          khi[ks][j] = h; klo[ks][j] = l2;
        }
      }
    }
#pragma unroll
    for (int ks = 0; ks < 2; ++ks){
      acc[t] = __builtin_amdgcn_mfma_f32_16x16x32_bf16(klo[ks], qhi[ks], acc[t], 0,0,0);
      acc[t] = __builtin_amdgcn_mfma_f32_16x16x32_bf16(khi[ks], qlo[ks], acc[t], 0,0,0);
      acc[t] = __builtin_amdgcn_mfma_f32_16x16x32_bf16(khi[ks], qhi[ks], acc[t], 0,0,0);
    }
  }

  // ---- Phase 2: softmax. Row q0+lr fully owned along (lg, r, t, wave).
  float mrow;
  {
    float mm = -3.4e38f;
#pragma unroll
    for (int t = 0; t < NT; ++t)
#pragma unroll
      for (int r = 0; r < 4; ++r) mm = fmaxf(mm, acc[t][r]);
    mm = fmaxf(mm, __shfl_xor(mm, 16, 64));
    mm = fmaxf(mm, __shfl_xor(mm, 32, 64));
    if (lane < 16) redm[wid][lane] = mm;
  }
  __syncthreads();
  {
    float mm = redm[0][lr];
#pragma unroll
    for (int w = 1; w < NW; ++w) mm = fmaxf(mm, redm[w][lr]);
    mrow = mm;
  }

  float inv;
  {
    float s = 0.f;
#pragma unroll
    for (int t = 0; t < NT; ++t)
#pragma unroll
      for (int r = 0; r < 4; ++r){
        float e = __expf(acc[t][r] - mrow);
        acc[t][r] = e;
        s += e;
      }
    s += __shfl_xor(s, 16, 64);
    s += __shfl_xor(s, 32, 64);
    if (lane < 16) redl[wid][lane] = s;
    __syncthreads();
    float tot = 0.f;
#pragma unroll
    for (int w = 0; w < NW; ++w) tot += redl[w][lr];
    inv = 1.0f / tot;
  }

  // ---- Phase 3+4: normalize, direct frag-layout nt weight stores, LDS pack, PV
  f32x4 oacc[4];
#pragma unroll
  for (int n = 0; n < 4; ++n) oacc[n] = (f32x4){0.f,0.f,0.f,0.f};

  float* wrow = wh + (size_t)(q0 + lr) * S + kw0 + lg*4;

#pragma unroll 1
  for (int c = 0; c < 4; ++c){
#pragma unroll
    for (int tt = 0; tt < 4; ++tt){
      const int t = 4*c + tt;
      f32x4 w4; u32x4 pw;
#pragma unroll
      for (int r = 0; r < 4; ++r){
        float w = acc[t][r] * inv;
        w4[r] = w;
        pw[r] = packsplit(w);
      }
      ntstore4(wrow + 16*t, w4);
      *reinterpret_cast<u32x4*>(&sW[wid][lr][16*tt + lg*4]) = pw;
    }
    const int kc = kw0 + 64*c;
#pragma unroll
    for (int ks = 0; ks < 2; ++ks){
      uint4 pa0 = *reinterpret_cast<const uint4*>(&sW[wid][lr][32*ks + lg*8]);
      uint4 pa1 = *reinterpret_cast<const uint4*>(&sW[wid][lr][32*ks + lg*8 + 4]);
      unsigned int pa[8] = {pa0.x,pa0.y,pa0.z,pa0.w,pa1.x,pa1.y,pa1.z,pa1.w};
      bf16x8 ahi, alo;
#pragma unroll
      for (int j = 0; j < 8; ++j){
        ahi[j] = (short)(pa[j] >> 16);
        alo[j] = (short)(pa[j] & 0xFFFFu);
      }
#pragma unroll
      for (int n = 0; n < 4; ++n){
        bf16x8 bhi, blo;
        if constexpr (PACKED){
          const unsigned int* vrow = vtph + (size_t)(16*n + lr) * S + kc + 32*ks + lg*8;
          uint4 pv0 = *reinterpret_cast<const uint4*>(vrow);
          uint4 pv1 = *reinterpret_cast<const uint4*>(vrow + 4);
          unsigned int pw[8] = {pv0.x,pv0.y,pv0.z,pv0.w,pv1.x,pv1.y,pv1.z,pv1.w};
#pragma unroll
          for (int j = 0; j < 8; ++j){
            bhi[j] = (short)(pw[j] >> 16);
            blo[j] = (short)(pw[j] & 0xFFFFu);
          }
        } else {
#pragma unroll
          for (int j = 0; j < 8; ++j){
            float x = vh[(size_t)(kc + 32*ks + lg*8 + j) * DD + 16*n + lr];
            short h, l2; split2(x, h, l2);
            bhi[j] = h; blo[j] = l2;
          }
        }
        oacc[n] = __builtin_amdgcn_mfma_f32_16x16x32_bf16(alo, bhi, oacc[n], 0,0,0);
        oacc[n] = __builtin_amdgcn_mfma_f32_16x16x32_bf16(ahi, blo, oacc[n], 0,0,0);
        oacc[n] = __builtin_amdgcn_mfma_f32_16x16x32_bf16(ahi, bhi, oacc[n], 0,0,0);
      }
    }
  }

  // ---- Phase 5: cross-wave reduction of out partials (alias sW)
  float (*sO)[16][68] = reinterpret_cast<float(*)[16][68]>(sW);
  __syncthreads();
#pragma unroll
  for (int n = 0; n < 4; ++n)
#pragma unroll
    for (int r = 0; r < 4; ++r)
      sO[wid][lg*4 + r][16*n + lr] = oacc[n][r];
  __syncthreads();
#pragma unroll
  for (int i = tid; i < 16*64; i += 512){
    int row = i >> 6, d = i & 63;
    float s = 0.f;
#pragma unroll
    for (int w = 0; w < NW; ++w) s += sO[w][row][d];
    __builtin_nontemporal_store(s, &oh[(size_t)(q0 + row) * DD + d]);
  }
}

extern "C" void kernel_launch(void* const* d_in, const int* in_sizes, int n_in,
                              void* d_out, int out_size, void* d_ws, size_t ws_size,
                              hipStream_t stream) {
  const float* q    = (const float*)d_in[0];
  const float* k    = (const float*)d_in[1];
  const float* v    = (const float*)d_in[2];
  const float* bias = (const float*)d_in[3];
  const float* gb   = (const float*)d_in[4];
  float* out  = (float*)d_out;
  float* wout = (float*)d_out + (size_t)NH * S * DD;

  const size_t nelem = (size_t)NH * S * DD;       // 4.19M
  const size_t need  = 2 * nelem * sizeof(unsigned int);

  dim3 grid(S / 16, NH);
  dim3 block(512);

  if (ws_size >= need){
    unsigned int* kp  = (unsigned int*)d_ws;
    unsigned int* vtp = kp + nelem;
    int n4 = (int)(nelem / 4);
    pack_k_kernel<<<(n4 + 255) / 256, 256, 0, stream>>>(k, kp, n4);
    pack_vt_kernel<<<NH * 32, 256, 0, stream>>>(v, vtp);
    attn_fused_kernel<true ><<<grid, block, 0, stream>>>(q, k, v, bias, gb, kp, vtp, out, wout);
  } else {
    attn_fused_kernel<false><<<grid, block, 0, stream>>>(q, k, v, bias, gb, nullptr, nullptr, out, wout);
  }
}